// Round 1
// baseline (282.353 us; speedup 1.0000x reference)
//
#include <hip/hip_runtime.h>

#define BINS 10

// ws layout: float bce_sum[BINS]; int counts[BINS]
// (harness poisons ws to 0xAA before every launch -> must zero it ourselves)

__global__ __launch_bounds__(64) void ghmc_zero(float* ws_sum, int* ws_cnt) {
    int i = threadIdx.x;
    if (i < BINS) { ws_sum[i] = 0.0f; ws_cnt[i] = 0; }
}

__device__ __forceinline__ void ghmc_elem(float pk, float tk, float wk,
                                          float lsum[BINS], int lcnt[BINS]) {
    if (wk > 0.0f) {
        // shared exp: e = exp(-|p|) in (0,1]
        float e = __expf(-fabsf(pk));
        float r = 1.0f / (1.0f + e);                 // sigmoid(|p|)
        float s = (pk >= 0.0f) ? r : (1.0f - r);     // sigmoid(p)
        float g = fabsf(s - tk);                     // in [0,1]
        int bin = (int)(g * 10.0f);                  // floor (g>=0)
        bin = bin > (BINS - 1) ? (BINS - 1) : bin;
        // stable softplus(p) - p*t
        float bce = fmaxf(pk, 0.0f) + log1pf(e) - pk * tk;
        // fully unrolled compare-chain: no dynamic register indexing / scratch
#pragma unroll
        for (int b = 0; b < BINS; ++b) {
            if (bin == b) { lsum[b] += bce; lcnt[b] += 1; }
        }
    }
}

__global__ __launch_bounds__(256) void ghmc_main(
    const float* __restrict__ pred, const float* __restrict__ targ,
    const float* __restrict__ lw,
    float* __restrict__ ws_sum, int* __restrict__ ws_cnt, int n) {

    float lsum[BINS];
    int   lcnt[BINS];
#pragma unroll
    for (int b = 0; b < BINS; ++b) { lsum[b] = 0.0f; lcnt[b] = 0; }

    const int tid    = blockIdx.x * blockDim.x + threadIdx.x;
    const int stride = gridDim.x * blockDim.x;
    const int nvec   = n >> 2;

    const float4* p4 = (const float4*)pred;
    const float4* t4 = (const float4*)targ;
    const float4* w4 = (const float4*)lw;

    for (int i = tid; i < nvec; i += stride) {
        float4 p = p4[i], t = t4[i], w = w4[i];
        const float* pp = (const float*)&p;
        const float* tt = (const float*)&t;
        const float* ww = (const float*)&w;
#pragma unroll
        for (int k = 0; k < 4; ++k)
            ghmc_elem(pp[k], tt[k], ww[k], lsum, lcnt);
    }
    // scalar tail (n not divisible by 4)
    {
        int rem = n & 3;
        if (tid < rem) {
            int i = (nvec << 2) + tid;
            ghmc_elem(pred[i], targ[i], lw[i], lsum, lcnt);
        }
    }

    // ---- wave (64-lane) butterfly reduction per bin ----
    __shared__ float s_sum[BINS];
    __shared__ int   s_cnt[BINS];
    if (threadIdx.x < BINS) { s_sum[threadIdx.x] = 0.0f; s_cnt[threadIdx.x] = 0; }
    __syncthreads();

    const int lane = threadIdx.x & 63;
#pragma unroll
    for (int b = 0; b < BINS; ++b) {
        float s = lsum[b];
        int   c = lcnt[b];
#pragma unroll
        for (int off = 32; off > 0; off >>= 1) {
            s += __shfl_xor(s, off, 64);
            c += __shfl_xor(c, off, 64);
        }
        if (lane == 0) {
            atomicAdd(&s_sum[b], s);   // 4 waves/block -> 40 LDS atomics total
            atomicAdd(&s_cnt[b], c);
        }
    }
    __syncthreads();

    if (threadIdx.x < BINS) {
        float s = s_sum[threadIdx.x];
        int   c = s_cnt[threadIdx.x];
        if (c != 0) {
            atomicAdd(&ws_sum[threadIdx.x], s);
            atomicAdd(&ws_cnt[threadIdx.x], c);
        }
    }
}

__global__ __launch_bounds__(64) void ghmc_finalize(
    const float* __restrict__ ws_sum, const int* __restrict__ ws_cnt,
    float* __restrict__ out) {
    if (threadIdx.x == 0) {
        float acc = 0.0f;
        int n = 0;
        for (int b = 0; b < BINS; ++b) {
            int c = ws_cnt[b];
            if (c > 0) { n += 1; acc += ws_sum[b] / (float)c; }
        }
        out[0] = (n > 0) ? (acc / (float)n) : 0.0f;  // LOSS_WEIGHT = 1
    }
}

extern "C" void kernel_launch(void* const* d_in, const int* in_sizes, int n_in,
                              void* d_out, int out_size, void* d_ws, size_t ws_size,
                              hipStream_t stream) {
    const float* pred = (const float*)d_in[0];
    const float* targ = (const float*)d_in[1];
    const float* lw   = (const float*)d_in[2];
    float* out = (float*)d_out;
    const int n = in_sizes[0];   // 262144*80 = 20,971,520

    float* ws_sum = (float*)d_ws;
    int*   ws_cnt = (int*)((char*)d_ws + BINS * sizeof(float));

    ghmc_zero<<<1, 64, 0, stream>>>(ws_sum, ws_cnt);

    const int threads = 256;
    const int blocks  = 2048;   // 8 blocks/CU on 256 CUs, grid-stride
    ghmc_main<<<blocks, threads, 0, stream>>>(pred, targ, lw, ws_sum, ws_cnt, n);

    ghmc_finalize<<<1, 64, 0, stream>>>(ws_sum, ws_cnt, out);
}